// Round 1
// baseline (242.236 us; speedup 1.0000x reference)
//
#include <hip/hip_runtime.h>

// EnvironmentalAugmentations: pink = AR(1) scan of white noise (a=0.99, b=0.01),
// mixed = waveform + 0.05*pink, out = mixed / max(|mixed|) if max > 1 else mixed.
// Shapes: (256 channels, 220500 samples), f32 in / f32 out.

#define TLEN 220500
#define CHANNELS 256

constexpr int CL   = 8192;          // samples per block (main chunk)
constexpr int H    = 1024;          // warm-up history: 0.99^1024 ~ 3.4e-5 -> negligible
constexpr int NT   = 256;           // threads per block
constexpr int SEG  = 32;            // CL / NT samples per thread
constexpr int WSEG = 4;             // H / NT warm samples per thread
constexpr int NCHUNK = (TLEN + CL - 1) / CL;   // 27

constexpr float AC = 0.99f;
constexpr float BC = 0.01f;
constexpr float NL = 0.05f;

constexpr double dpow(double a, int n) { double r = 1.0; for (int i = 0; i < n; ++i) r *= a; return r; }
constexpr float A_SEG  = (float)dpow(0.99, SEG);   // 0.99^32
constexpr float A_WSEG = (float)dpow(0.99, WSEG);  // 0.99^4

// Padded LDS layouts: row stride 33 (main) / 5 (warm) floats -> conflict-free
// serial per-thread reads (bank = (tid + k) % 32 spreads across all banks).
__device__ __forceinline__ int maddr(int j) { return (j >> 5) * 33 + (j & 31); }
__device__ __forceinline__ int waddr(int j) { return (j >> 2) * 5 + (j & 3); }

__global__ void init_max_kernel(unsigned int* gmax) { *gmax = 0u; }

__global__ __launch_bounds__(NT, 4)
void pink_mix_kernel(const float* __restrict__ waveform,
                     const float* __restrict__ white,
                     float* __restrict__ out,
                     unsigned int* __restrict__ gmax)
{
    __shared__ float lm[NT * 33];        // main chunk, padded   (33 KB)
    __shared__ float lw[NT * 5];         // warm-up chunk, padded ( 5 KB)
    __shared__ float sA[4], sB[4], swA[4], swB[4], sM[4];

    const int chunk = blockIdx.x;
    const int ch    = blockIdx.y;
    const int c0    = chunk * CL;
    const size_t rowoff = (size_t)ch * TLEN;
    const float* __restrict__ wrow = white + rowoff;
    const float* __restrict__ arow = waveform + rowoff;
    float* __restrict__ orow = out + rowoff;

    const int tid  = threadIdx.x;
    const int lane = tid & 63;
    const int wv   = tid >> 6;

    // ---- coalesced load: main chunk (zero-fill past TLEN) ----
    #pragma unroll
    for (int i = 0; i < SEG / 4; ++i) {          // 8 float4s per thread
        int j4 = i * NT + tid;                   // float4 index in chunk
        int g  = c0 + 4 * j4;
        float4 v = make_float4(0.f, 0.f, 0.f, 0.f);
        if (g < TLEN) v = *reinterpret_cast<const float4*>(wrow + g);
        int base = maddr(4 * j4);
        lm[base] = v.x; lm[base + 1] = v.y; lm[base + 2] = v.z; lm[base + 3] = v.w;
    }
    // ---- coalesced load: warm-up region [c0-H, c0) (chunk>0 only; c0>=8192>H) ----
    if (chunk > 0) {
        int g = c0 - H + 4 * tid;
        float4 v = *reinterpret_cast<const float4*>(wrow + g);
        int base = waddr(4 * tid);
        lw[base] = v.x; lw[base + 1] = v.y; lw[base + 2] = v.z; lw[base + 3] = v.w;
    }
    __syncthreads();

    // Stash w[0] NOW (phase 3 overwrites lm after the next barrier).
    const float w0first = lm[0];

    // ---- warm-up scan: total affine transform over H samples applied to 0 ----
    if (chunk > 0) {
        float f = 0.f;
        #pragma unroll
        for (int k = 0; k < WSEG; ++k)
            f = fmaf(AC, f, BC * lw[tid * 5 + k]);
        float pA = A_WSEG, pB = f;
        #pragma unroll
        for (int d = 1; d < 64; d <<= 1) {
            float oA = __shfl_up(pA, d, 64);
            float oB = __shfl_up(pB, d, 64);
            if (lane >= d) { pB = fmaf(pA, oB, pB); pA *= oA; }
        }
        if (lane == 63) { swA[wv] = pA; swB[wv] = pB; }
    }

    // ---- main local scan (from 0) + wave inclusive pair-scan ----
    float f = 0.f;
    #pragma unroll
    for (int k = 0; k < SEG; ++k)
        f = fmaf(AC, f, BC * lm[tid * 33 + k]);
    float pA = A_SEG, pB = f;
    #pragma unroll
    for (int d = 1; d < 64; d <<= 1) {
        float oA = __shfl_up(pA, d, 64);
        float oB = __shfl_up(pB, d, 64);
        if (lane >= d) { pB = fmaf(pA, oB, pB); pA *= oA; }
    }
    float eA = __shfl_up(pA, 1, 64);   // lane-exclusive
    float eB = __shfl_up(pB, 1, 64);
    if (lane == 0) { eA = 1.f; eB = 0.f; }
    if (lane == 63) { sA[wv] = pA; sB[wv] = pB; }
    __syncthreads();

    // chunk entry state: warm-up total (chunk>0) or w[0] (chunk 0; a*w0+b*w0 = w0)
    float fin;
    if (chunk > 0) {
        float tA = swA[0], tB = swB[0];
        #pragma unroll
        for (int w = 1; w < 4; ++w) { tB = fmaf(swA[w], tB, swB[w]); tA *= swA[w]; }
        fin = tB;
    } else {
        fin = w0first;
    }

    // wave-exclusive prefix over wave totals
    float wA = 1.f, wB = 0.f;
    for (int w = 0; w < wv; ++w) { wB = fmaf(sA[w], wB, sB[w]); wA *= sA[w]; }
    // thread-exclusive = lane_excl o wave_excl
    float tA = eA * wA;
    float tB = fmaf(eA, wB, eB);
    float fe = fmaf(tA, fin, tB);      // state entering this thread's segment

    // ---- phase 3: re-scan with correct entry state; write pink back into lm ----
    f = fe;
    #pragma unroll
    for (int k = 0; k < SEG; ++k) {
        int a = tid * 33 + k;
        float w = lm[a];
        f = fmaf(AC, f, BC * w);
        lm[a] = f;
    }
    __syncthreads();

    // ---- epilogue: mixed = waveform + 0.05*pink, coalesced store, block max ----
    float mx = 0.f;
    #pragma unroll
    for (int i = 0; i < SEG / 4; ++i) {
        int j4 = i * NT + tid;
        int g  = c0 + 4 * j4;
        if (g < TLEN) {
            int base = maddr(4 * j4);
            float4 wf = *reinterpret_cast<const float4*>(arow + g);
            float4 m;
            m.x = fmaf(NL, lm[base],     wf.x);
            m.y = fmaf(NL, lm[base + 1], wf.y);
            m.z = fmaf(NL, lm[base + 2], wf.z);
            m.w = fmaf(NL, lm[base + 3], wf.w);
            *reinterpret_cast<float4*>(orow + g) = m;
            mx = fmaxf(mx, fmaxf(fmaxf(fabsf(m.x), fabsf(m.y)),
                                 fmaxf(fabsf(m.z), fabsf(m.w))));
        }
    }
    #pragma unroll
    for (int d = 32; d >= 1; d >>= 1)
        mx = fmaxf(mx, __shfl_xor(mx, d, 64));
    if (lane == 0) sM[wv] = mx;
    __syncthreads();
    if (tid == 0) {
        float m = fmaxf(fmaxf(sM[0], sM[1]), fmaxf(sM[2], sM[3]));
        atomicMax(gmax, __float_as_uint(m));   // all values >= 0: uint order == float order
    }
}

__global__ __launch_bounds__(256)
void scale_kernel(float* __restrict__ out, const unsigned int* __restrict__ gmax, int n4)
{
    const float m = __uint_as_float(*gmax);
    const float s = (m > 1.0f) ? (1.0f / m) : 1.0f;
    float4* p = reinterpret_cast<float4*>(out);
    int i = blockIdx.x * blockDim.x + threadIdx.x;
    const int stride = gridDim.x * blockDim.x;
    for (; i < n4; i += stride) {
        float4 v = p[i];
        v.x *= s; v.y *= s; v.z *= s; v.w *= s;
        p[i] = v;
    }
}

extern "C" void kernel_launch(void* const* d_in, const int* in_sizes, int n_in,
                              void* d_out, int out_size, void* d_ws, size_t ws_size,
                              hipStream_t stream)
{
    const float* waveform = (const float*)d_in[0];
    const float* white    = (const float*)d_in[1];
    float* out            = (float*)d_out;
    unsigned int* gmax    = (unsigned int*)d_ws;

    hipLaunchKernelGGL(init_max_kernel, dim3(1), dim3(1), 0, stream, gmax);

    dim3 grid(NCHUNK, CHANNELS);           // 27 x 256 blocks
    hipLaunchKernelGGL(pink_mix_kernel, grid, dim3(NT), 0, stream,
                       waveform, white, out, gmax);

    const int n4 = out_size / 4;           // 14,112,000 float4s (out_size % 4 == 0)
    hipLaunchKernelGGL(scale_kernel, dim3(2048), dim3(256), 0, stream,
                       out, gmax, n4);
}